// Round 7
// baseline (239.911 us; speedup 1.0000x reference)
//
#include <hip/hip_runtime.h>

namespace {

constexpr int kN = 100;   // subactors
constexpr int kH = 16;    // hidden
constexpr int kS = 6;     // state
constexpr int kB = 128;   // batch
constexpr int kT = 128;   // time
constexpr int kNS = kN * kS;   // 600 floats per (b,t) row
constexpr int kXB = kT * kNS;  // 76800 floats per b

typedef float f32x4 __attribute__((ext_vector_type(4)));
typedef short bf16x8 __attribute__((ext_vector_type(8)));

union Frag {
  unsigned u[4];
  bf16x8 v;
};

// RNE pack of two f32 into one dword of two bf16 (low = a). Manual bit twiddle
// (__hip_bfloat162 is not trivially copyable -> no __builtin_bit_cast on it).
__device__ __forceinline__ unsigned pkbf(float a, float b) {
  unsigned ua = __builtin_bit_cast(unsigned, a);
  unsigned ub = __builtin_bit_cast(unsigned, b);
  ua += 0x7fffu + ((ua >> 16) & 1u);
  ub += 0x7fffu + ((ub >> 16) & 1u);
  return (ua >> 16) | (ub & 0xffff0000u);
}

__device__ __forceinline__ float rcp_fast(float v) {
  return __builtin_amdgcn_rcpf(v);
}
__device__ __forceinline__ float sigm(float v) {
  return rcp_fast(1.0f + __expf(-v));
}
__device__ __forceinline__ float tanh_fast(float v) {
  return 1.0f - 2.0f * rcp_fast(1.0f + __expf(2.0f * v));
}

__device__ __forceinline__ f32x4 mfma16(bf16x8 a, bf16x8 b, f32x4 c) {
  return __builtin_amdgcn_mfma_f32_16x16x32_bf16(a, b, c, 0, 0, 0);
}

// Build a static A fragment: rows j, K = [h(16) | x(6) | 0...].
// A layout (HW-verified): m = lane&15, k = qt*8 + i.
__device__ __forceinline__ void mkA(Frag& F, int qt, const float* hrow,
                                    const float* xrow) {
  F.u[0] = F.u[1] = F.u[2] = F.u[3] = 0u;
  if (qt == 0 && hrow) {
    F.u[0] = pkbf(hrow[0], hrow[1]);
    F.u[1] = pkbf(hrow[2], hrow[3]);
    F.u[2] = pkbf(hrow[4], hrow[5]);
    F.u[3] = pkbf(hrow[6], hrow[7]);
  }
  if (qt == 1 && hrow) {
    F.u[0] = pkbf(hrow[8], hrow[9]);
    F.u[1] = pkbf(hrow[10], hrow[11]);
    F.u[2] = pkbf(hrow[12], hrow[13]);
    F.u[3] = pkbf(hrow[14], hrow[15]);
  }
  if (qt == 2 && xrow) {  // k 16..21 = x, rest 0
    F.u[0] = pkbf(xrow[0], xrow[1]);
    F.u[1] = pkbf(xrow[2], xrow[3]);
    F.u[2] = pkbf(xrow[4], xrow[5]);
  }
}

}  // namespace

// Monolithic, TWO batch-tiles interleaved per wave. Wave = (n, tile-pair
// {bp, bp+4}). The two serial chains are independent -> their bpermute
// latency, MFMA latency and transcendental chains overlap inside the wave.
// No LDS arrays, no barriers, no workspace (avoids ws re-poison overhead).
__global__ __launch_bounds__(64) void actor_mfma2(
    const float* __restrict__ x, const float* __restrict__ Wih,
    const float* __restrict__ Whh, const float* __restrict__ bih,
    const float* __restrict__ bhh, const float* __restrict__ W1,
    const float* __restrict__ b1, const float* __restrict__ W2,
    const float* __restrict__ b2, const float* __restrict__ W3,
    const float* __restrict__ b3, float* __restrict__ out) {
  const int tid = (int)threadIdx.x;
  const int j = tid & 15;
  const int qt = tid >> 4;
  const int n = (int)blockIdx.x >> 2;
  const int bp = (int)blockIdx.x & 3;

  // ---- shared per-n weight fragments (A operands) ----
  Frag Ar, Az, Anh, Anx, Ay1, Ay2;
  mkA(Ar, qt, Whh + ((size_t)n * 48 + j) * 16, Wih + ((size_t)n * 48 + j) * 6);
  mkA(Az, qt, Whh + ((size_t)n * 48 + 16 + j) * 16,
      Wih + ((size_t)n * 48 + 16 + j) * 6);
  mkA(Anh, qt, Whh + ((size_t)n * 48 + 32 + j) * 16, nullptr);
  mkA(Anx, qt, nullptr, Wih + ((size_t)n * 48 + 32 + j) * 6);
  mkA(Ay1, qt, W1 + ((size_t)n * 16 + j) * 16, nullptr);
  mkA(Ay2, qt, W2 + ((size_t)n * 16 + j) * 16, nullptr);

  float br_[4], bz_[4], bin_[4], bhn_[4], b1e[4], b2e[4], w3r[4];
#pragma unroll
  for (int r = 0; r < 4; ++r) {
    const int gi = n * 48 + 4 * qt + r;
    br_[r] = bih[gi] + bhh[gi];
    bz_[r] = bih[gi + 16] + bhh[gi + 16];
    bin_[r] = bih[gi + 32];
    bhn_[r] = bhh[gi + 32];
    const int hi = n * 16 + 4 * qt + r;
    b1e[r] = b1[hi];
    b2e[r] = b2[hi];
    w3r[r] = W3[hi];
  }
  const float b3s = b3[n];

  const int a_lo = (j + 32 * (qt & 1)) * 4;
  const int a_hi = a_lo + 64;
  const bool hquad = (qt < 2);
  const bool xquad = (qt == 2);

  const f32x4 zero4 = {0.f, 0.f, 0.f, 0.f};

  // ---- per-tile state ----
  const float* px[2];
  float* outp[2];
  float hprev[2][4];
  unsigned P0[2], P1[2];
  float2 xa[2][2][3];  // [tile][ring slot][3 float2]

#pragma unroll
  for (int i = 0; i < 2; ++i) {
    const int bt = bp + 4 * i;
    const int b = bt * 16 + j;
    px[i] = x + (size_t)b * kXB + (size_t)n * kS;
    outp[i] = out + ((size_t)n * kB + b) * kT;
#pragma unroll
    for (int r = 0; r < 4; ++r) hprev[i][r] = 0.f;
    P0[i] = 0u;
    P1[i] = 0u;
#pragma unroll
    for (int s = 0; s < 2; ++s) {
      const float* xp = px[i] + (size_t)s * kNS;
      xa[i][s][0] = *(const float2*)(xp + 0);
      xa[i][s][1] = *(const float2*)(xp + 2);
      xa[i][s][2] = *(const float2*)(xp + 4);
    }
  }

  // Y tail for step tout, from Cy1 of tile i (off the recurrence chain).
  auto doY = [&](int i, const f32x4& Cy1, int tout) {
    float y1v[4];
#pragma unroll
    for (int r = 0; r < 4; ++r) y1v[r] = fmaxf(Cy1[r] + b1e[r], 0.f);
    const unsigned Q0 = pkbf(y1v[0], y1v[1]);
    const unsigned Q1 = pkbf(y1v[2], y1v[3]);
    const int yb0 = __builtin_amdgcn_ds_bpermute(a_lo, (int)Q0);
    const int yb1 = __builtin_amdgcn_ds_bpermute(a_lo, (int)Q1);
    const int yb2 = __builtin_amdgcn_ds_bpermute(a_hi, (int)Q0);
    const int yb3 = __builtin_amdgcn_ds_bpermute(a_hi, (int)Q1);
    Frag By;
    By.u[0] = hquad ? (unsigned)yb0 : 0u;
    By.u[1] = hquad ? (unsigned)yb1 : 0u;
    By.u[2] = hquad ? (unsigned)yb2 : 0u;
    By.u[3] = hquad ? (unsigned)yb3 : 0u;
    const f32x4 Cy2 = mfma16(Ay2.v, By.v, zero4);
    float s = 0.f;
#pragma unroll
    for (int r = 0; r < 4; ++r) s += fmaxf(Cy2[r] + b2e[r], 0.f) * w3r[r];
    s += __shfl_xor(s, 16);
    s += __shfl_xor(s, 32);
    const float y3 = fmaxf(s + b3s, 0.f);
    if (tout >= 0 && qt == 0) outp[i][tout] = y3;
  };

  // One recurrence step of tile i at time t (ring slot = t&1).
  auto doStep = [&](int i, int t) {
    const int sl = t & 1;
    // B-operand h-part from the carried packed h
    const int bp0 = __builtin_amdgcn_ds_bpermute(a_lo, (int)P0[i]);
    const int bp1 = __builtin_amdgcn_ds_bpermute(a_lo, (int)P1[i]);
    const int bp2 = __builtin_amdgcn_ds_bpermute(a_hi, (int)P0[i]);
    const int bp3 = __builtin_amdgcn_ds_bpermute(a_hi, (int)P1[i]);
    const unsigned xd0 = pkbf(xa[i][sl][0].x, xa[i][sl][0].y);
    const unsigned xd1 = pkbf(xa[i][sl][1].x, xa[i][sl][1].y);
    const unsigned xd2 = pkbf(xa[i][sl][2].x, xa[i][sl][2].y);
    Frag Bf;
    Bf.u[0] = hquad ? (unsigned)bp0 : (xquad ? xd0 : 0u);
    Bf.u[1] = hquad ? (unsigned)bp1 : (xquad ? xd1 : 0u);
    Bf.u[2] = hquad ? (unsigned)bp2 : (xquad ? xd2 : 0u);
    Bf.u[3] = hquad ? (unsigned)bp3 : 0u;

    // reload ring slot with x_{t+2}
    {
      int tc = t + 2;
      if (tc > kT - 1) tc = kT - 1;
      const float* xp = px[i] + (size_t)tc * kNS;
      xa[i][sl][0] = *(const float2*)(xp + 0);
      xa[i][sl][1] = *(const float2*)(xp + 2);
      xa[i][sl][2] = *(const float2*)(xp + 4);
    }

    const f32x4 Cr = mfma16(Ar.v, Bf.v, zero4);    // xr + hr
    const f32x4 Cz = mfma16(Az.v, Bf.v, zero4);    // xz + hz
    const f32x4 Chn = mfma16(Anh.v, Bf.v, zero4);  // hn only
    const f32x4 Cxn = mfma16(Anx.v, Bf.v, zero4);  // xn only
    const f32x4 Cy1 = mfma16(Ay1.v, Bf.v, zero4);  // y1 of step t-1

    doY(i, Cy1, t - 1);

    // gate epilogue -> h_t
#pragma unroll
    for (int r = 0; r < 4; ++r) {
      const float rr = sigm(Cr[r] + br_[r]);
      const float zz = sigm(Cz[r] + bz_[r]);
      const float nn =
          tanh_fast((Cxn[r] + bin_[r]) + rr * (Chn[r] + bhn_[r]));
      hprev[i][r] = nn + zz * (hprev[i][r] - nn);
    }
    P0[i] = pkbf(hprev[i][0], hprev[i][1]);
    P1[i] = pkbf(hprev[i][2], hprev[i][3]);
  };

  for (int t2 = 0; t2 < kT; t2 += 2) {
#pragma unroll
    for (int k = 0; k < 2; ++k) {
      const int t = t2 + k;
      doStep(0, t);
      doStep(1, t);
    }
  }

  // drain: y for t = kT-1 from the final h of each tile
#pragma unroll
  for (int i = 0; i < 2; ++i) {
    const int bp0 = __builtin_amdgcn_ds_bpermute(a_lo, (int)P0[i]);
    const int bp1 = __builtin_amdgcn_ds_bpermute(a_lo, (int)P1[i]);
    const int bp2 = __builtin_amdgcn_ds_bpermute(a_hi, (int)P0[i]);
    const int bp3 = __builtin_amdgcn_ds_bpermute(a_hi, (int)P1[i]);
    Frag Bf;
    Bf.u[0] = hquad ? (unsigned)bp0 : 0u;
    Bf.u[1] = hquad ? (unsigned)bp1 : 0u;
    Bf.u[2] = hquad ? (unsigned)bp2 : 0u;
    Bf.u[3] = hquad ? (unsigned)bp3 : 0u;
    const f32x4 Cy1 = mfma16(Ay1.v, Bf.v, zero4);
    doY(i, Cy1, kT - 1);
  }
}

extern "C" void kernel_launch(void* const* d_in, const int* in_sizes, int n_in,
                              void* d_out, int out_size, void* d_ws,
                              size_t ws_size, hipStream_t stream) {
  const float* x = (const float*)d_in[0];
  const float* Wih = (const float*)d_in[1];
  const float* Whh = (const float*)d_in[2];
  const float* bih = (const float*)d_in[3];
  const float* bhh = (const float*)d_in[4];
  const float* W1 = (const float*)d_in[5];
  const float* b1 = (const float*)d_in[6];
  const float* W2 = (const float*)d_in[7];
  const float* b2 = (const float*)d_in[8];
  const float* W3 = (const float*)d_in[9];
  const float* b3 = (const float*)d_in[10];
  float* out = (float*)d_out;

  actor_mfma2<<<dim3(kN * 4), dim3(64), 0, stream>>>(x, Wih, Whh, bih, bhh, W1,
                                                     b1, W2, b2, W3, b3, out);
}

// Round 8
// 158.567 us; speedup vs baseline: 1.5130x; 1.5130x over previous
//
#include <hip/hip_runtime.h>

namespace {

constexpr int kN = 100;   // subactors
constexpr int kH = 16;    // hidden
constexpr int kS = 6;     // state
constexpr int kB = 128;   // batch
constexpr int kT = 128;   // time
constexpr int kNS = kN * kS;   // 600 floats per (b,t) row
constexpr int kXB = kT * kNS;  // 76800 floats per b

typedef float f32x4 __attribute__((ext_vector_type(4)));
typedef short bf16x8 __attribute__((ext_vector_type(8)));

union Frag {
  unsigned u[4];
  bf16x8 v;
};

// RNE pack of two f32 into one dword of two bf16 (low = a).
__device__ __forceinline__ unsigned pkbf(float a, float b) {
  unsigned ua = __builtin_bit_cast(unsigned, a);
  unsigned ub = __builtin_bit_cast(unsigned, b);
  ua += 0x7fffu + ((ua >> 16) & 1u);
  ub += 0x7fffu + ((ub >> 16) & 1u);
  return (ua >> 16) | (ub & 0xffff0000u);
}

__device__ __forceinline__ float rcp_fast(float v) {
  return __builtin_amdgcn_rcpf(v);
}
__device__ __forceinline__ float sigm(float v) {
  return rcp_fast(1.0f + __expf(-v));
}
__device__ __forceinline__ float tanh_fast(float v) {
  return 1.0f - 2.0f * rcp_fast(1.0f + __expf(2.0f * v));
}

__device__ __forceinline__ f32x4 mfma16(bf16x8 a, bf16x8 b, f32x4 c) {
  return __builtin_amdgcn_mfma_f32_16x16x32_bf16(a, b, c, 0, 0, 0);
}

// K-slot permutation chosen for B-locality (A and B just have to agree):
//   quad q supplies k-slots: [8q..8q+3] = h rows 4q..4q+3
//                            [8q+4,8q+5] = x comps 2q,2q+1  (q<3)
//                            rest 0
// A fragment for output-row m = lane&15, quad qA = lane>>4:
//   u[0] = (Wh[m][4qA+0], Wh[m][4qA+1])   u[1] = (Wh[m][4qA+2], Wh[m][4qA+3])
//   u[2] = qA<3 ? (Wx[m][2qA], Wx[m][2qA+1]) : 0    u[3] = 0
__device__ __forceinline__ void mkA(Frag& F, int qt, const float* hrow,
                                    const float* xrow) {
  F.u[0] = F.u[1] = F.u[2] = F.u[3] = 0u;
  if (hrow) {
    F.u[0] = pkbf(hrow[4 * qt + 0], hrow[4 * qt + 1]);
    F.u[1] = pkbf(hrow[4 * qt + 2], hrow[4 * qt + 3]);
  }
  if (xrow && qt < 3) {
    F.u[2] = pkbf(xrow[2 * qt + 0], xrow[2 * qt + 1]);
  }
}

}  // namespace

// Wave = (n, 16-batch tile), 800 waves. The K-permutation above makes the
// B operand fully lane-local: B is packed from the lane's own h (C-layout
// rows 4qt..4qt+3 of its own column) and its own x. NO cross-lane ops on
// the recurrence chain; the only DS ops are 2 shfl_xor in the W3 reduce.
__global__ __launch_bounds__(64) void actor_local(
    const float* __restrict__ x, const float* __restrict__ Wih,
    const float* __restrict__ Whh, const float* __restrict__ bih,
    const float* __restrict__ bhh, const float* __restrict__ W1,
    const float* __restrict__ b1, const float* __restrict__ W2,
    const float* __restrict__ b2, const float* __restrict__ W3,
    const float* __restrict__ b3, float* __restrict__ out) {
  const int tid = (int)threadIdx.x;
  const int j = tid & 15;   // output-row m for A; batch-col for B/C
  const int qt = tid >> 4;  // quad = k-group (A/B), row-group (C)
  const int n = (int)blockIdx.x >> 3;
  const int bt = (int)blockIdx.x & 7;

  // ---- A fragments (weights), K-permuted as above ----
  Frag Ar, Az, Anh, Anx, Ay1, Ay2;
  mkA(Ar, qt, Whh + ((size_t)n * 48 + j) * 16, Wih + ((size_t)n * 48 + j) * 6);
  mkA(Az, qt, Whh + ((size_t)n * 48 + 16 + j) * 16,
      Wih + ((size_t)n * 48 + 16 + j) * 6);
  mkA(Anh, qt, Whh + ((size_t)n * 48 + 32 + j) * 16, nullptr);
  mkA(Anx, qt, nullptr, Wih + ((size_t)n * 48 + 32 + j) * 6);
  mkA(Ay1, qt, W1 + ((size_t)n * 16 + j) * 16, nullptr);
  mkA(Ay2, qt, W2 + ((size_t)n * 16 + j) * 16, nullptr);

  // ---- per-lane bias/constant regs (C rows 4*qt..4*qt+3) ----
  float br_[4], bz_[4], bin_[4], bhn_[4], b1e[4], b2e[4], w3r[4];
#pragma unroll
  for (int r = 0; r < 4; ++r) {
    const int gi = n * 48 + 4 * qt + r;
    br_[r] = bih[gi] + bhh[gi];
    bz_[r] = bih[gi + 16] + bhh[gi + 16];
    bin_[r] = bih[gi + 32];
    bhn_[r] = bhh[gi + 32];
    const int hi = n * 16 + 4 * qt + r;
    b1e[r] = b1[hi];
    b2e[r] = b2[hi];
    w3r[r] = W3[hi];
  }
  const float b3s = b3[n];

  const int b = bt * 16 + j;
  const float* px = x + (size_t)b * kXB + (size_t)n * kS + (qt < 3 ? 2 * qt : 0);
  float* outp = out + ((size_t)n * kB + b) * kT;

  const f32x4 zero4 = {0.f, 0.f, 0.f, 0.f};

  // x ring: this lane only needs its quad's 2 components (1 float2), depth 2
  float2 xr[2];
  xr[0] = *(const float2*)(px + 0 * kNS);
  xr[1] = *(const float2*)(px + 1 * kNS);

  float hprev[4] = {0.f, 0.f, 0.f, 0.f};
  unsigned P0 = 0u, P1 = 0u;  // packed own-h (B slots), carried

  // y tail: Cy1 (y1 pre-act of some step) -> y2 -> y3 -> store
  auto doY = [&](const f32x4& Cy1, int tout) {
    float y1v[4];
#pragma unroll
    for (int r = 0; r < 4; ++r) y1v[r] = fmaxf(Cy1[r] + b1e[r], 0.f);
    Frag By;
    By.u[0] = pkbf(y1v[0], y1v[1]);  // own y1 rows -> own B slots
    By.u[1] = pkbf(y1v[2], y1v[3]);
    By.u[2] = 0u;
    By.u[3] = 0u;
    const f32x4 Cy2 = mfma16(Ay2.v, By.v, zero4);
    float s = 0.f;
#pragma unroll
    for (int r = 0; r < 4; ++r) s += fmaxf(Cy2[r] + b2e[r], 0.f) * w3r[r];
    s += __shfl_xor(s, 16);
    s += __shfl_xor(s, 32);
    const float y3 = fmaxf(s + b3s, 0.f);
    if (tout >= 0 && qt == 0) outp[tout] = y3;
  };

  for (int t2 = 0; t2 < kT; t2 += 2) {
#pragma unroll
    for (int k = 0; k < 2; ++k) {
      const int t = t2 + k;
      // B: fully lane-local (own h pack + own x pack)
      Frag Bf;
      Bf.u[0] = P0;
      Bf.u[1] = P1;
      Bf.u[2] = (qt < 3) ? pkbf(xr[k].x, xr[k].y) : 0u;
      Bf.u[3] = 0u;

      // reload ring slot with x_{t+2}
      {
        int tc = t + 2;
        if (tc > kT - 1) tc = kT - 1;
        xr[k] = *(const float2*)(px + (size_t)tc * kNS);
      }

      const f32x4 Cr = mfma16(Ar.v, Bf.v, zero4);    // xr + hr
      const f32x4 Cz = mfma16(Az.v, Bf.v, zero4);    // xz + hz
      const f32x4 Chn = mfma16(Anh.v, Bf.v, zero4);  // hn only
      const f32x4 Cxn = mfma16(Anx.v, Bf.v, zero4);  // xn only
      const f32x4 Cy1 = mfma16(Ay1.v, Bf.v, zero4);  // y1 of step t-1

      doY(Cy1, t - 1);  // off the recurrence chain

      // gate epilogue -> h_t (each quad owns rows 4qt..4qt+3)
#pragma unroll
      for (int r = 0; r < 4; ++r) {
        const float rr = sigm(Cr[r] + br_[r]);
        const float zz = sigm(Cz[r] + bz_[r]);
        const float nn =
            tanh_fast((Cxn[r] + bin_[r]) + rr * (Chn[r] + bhn_[r]));
        hprev[r] = nn + zz * (hprev[r] - nn);
      }
      P0 = pkbf(hprev[0], hprev[1]);
      P1 = pkbf(hprev[2], hprev[3]);
    }
  }

  // drain: y for t = kT-1 from the final h
  {
    Frag Bf;
    Bf.u[0] = P0;
    Bf.u[1] = P1;
    Bf.u[2] = 0u;
    Bf.u[3] = 0u;
    const f32x4 Cy1 = mfma16(Ay1.v, Bf.v, zero4);
    doY(Cy1, kT - 1);
  }
}

extern "C" void kernel_launch(void* const* d_in, const int* in_sizes, int n_in,
                              void* d_out, int out_size, void* d_ws,
                              size_t ws_size, hipStream_t stream) {
  const float* x = (const float*)d_in[0];
  const float* Wih = (const float*)d_in[1];
  const float* Whh = (const float*)d_in[2];
  const float* bih = (const float*)d_in[3];
  const float* bhh = (const float*)d_in[4];
  const float* W1 = (const float*)d_in[5];
  const float* b1 = (const float*)d_in[6];
  const float* W2 = (const float*)d_in[7];
  const float* b2 = (const float*)d_in[8];
  const float* W3 = (const float*)d_in[9];
  const float* b3 = (const float*)d_in[10];
  float* out = (float*)d_out;

  actor_local<<<dim3(kN * 8), dim3(64), 0, stream>>>(x, Wih, Whh, bih, bhh, W1,
                                                     b1, W2, b2, W3, b3, out);
}

// Round 9
// 143.908 us; speedup vs baseline: 1.6671x; 1.1019x over previous
//
#include <hip/hip_runtime.h>

namespace {

constexpr int kN = 100;   // subactors
constexpr int kH = 16;    // hidden
constexpr int kS = 6;     // state
constexpr int kB = 128;   // batch
constexpr int kT = 128;   // time
constexpr int kNS = kN * kS;   // 600 floats per (b,t) row
constexpr int kXB = kT * kNS;  // 76800 floats per b
constexpr float kL2E = 1.44269504088896340736f;  // log2(e)

typedef float f32x4 __attribute__((ext_vector_type(4)));
typedef short bf16x8 __attribute__((ext_vector_type(8)));

union Frag {
  unsigned u[4];
  bf16x8 v;
};

// RNE pack of two f32 into one dword of two bf16 (low = a).
__device__ __forceinline__ unsigned pkbf(float a, float b) {
  unsigned ua = __builtin_bit_cast(unsigned, a);
  unsigned ub = __builtin_bit_cast(unsigned, b);
  ua += 0x7fffu + ((ua >> 16) & 1u);
  ub += 0x7fffu + ((ub >> 16) & 1u);
  return (ua >> 16) | (ub & 0xffff0000u);
}

__device__ __forceinline__ float rcp_fast(float v) {
  return __builtin_amdgcn_rcpf(v);
}
__device__ __forceinline__ float exp2_fast(float v) {
  return __builtin_amdgcn_exp2f(v);
}

__device__ __forceinline__ f32x4 mfma16(bf16x8 a, bf16x8 b, f32x4 c) {
  return __builtin_amdgcn_mfma_f32_16x16x32_bf16(a, b, c, 0, 0, 0);
}

// K-slot permutation for lane-local B (A and B just have to agree):
//   quad q supplies k-slots [8q..8q+3] = h rows 4q..4q+3,
//   [8q+4,8q+5] = x comps 2q,2q+1 (q<3), rest 0.
// Weights pre-scaled by sc (folds log2e into the MFMA).
__device__ __forceinline__ void mkA(Frag& F, int qt, const float* hrow,
                                    const float* xrow, float sc) {
  F.u[0] = F.u[1] = F.u[2] = F.u[3] = 0u;
  if (hrow) {
    F.u[0] = pkbf(hrow[4 * qt + 0] * sc, hrow[4 * qt + 1] * sc);
    F.u[1] = pkbf(hrow[4 * qt + 2] * sc, hrow[4 * qt + 3] * sc);
  }
  if (xrow && qt < 3) {
    F.u[2] = pkbf(xrow[2 * qt + 0] * sc, xrow[2 * qt + 1] * sc);
  }
}

}  // namespace

// Wave = (n, 16-batch tile), 800 waves, lane-local B operands (round 8).
// New: y-path software-pipelined 2 deep (no MFMA-result waits), 16-lane
// reduce batched every 4 steps (8 independent shfls, one float4 store),
// biases folded into MFMA C operands, exp2-native activations via
// log2e-prescaled weights.
__global__ __launch_bounds__(64) void actor_pipe(
    const float* __restrict__ x, const float* __restrict__ Wih,
    const float* __restrict__ Whh, const float* __restrict__ bih,
    const float* __restrict__ bhh, const float* __restrict__ W1,
    const float* __restrict__ b1, const float* __restrict__ W2,
    const float* __restrict__ b2, const float* __restrict__ W3,
    const float* __restrict__ b3, float* __restrict__ out) {
  const int tid = (int)threadIdx.x;
  const int j = tid & 15;   // output-row m for A; batch-col for B/C
  const int qt = tid >> 4;  // quad = k-group (A/B), row-group (C)
  const int n = (int)blockIdx.x >> 3;
  const int bt = (int)blockIdx.x & 7;

  // ---- A fragments (weights), K-permuted, log2e-prescaled ----
  Frag Ar, Az, Anh, Anx, Ay1, Ay2;
  mkA(Ar, qt, Whh + ((size_t)n * 48 + j) * 16, Wih + ((size_t)n * 48 + j) * 6,
      kL2E);
  mkA(Az, qt, Whh + ((size_t)n * 48 + 16 + j) * 16,
      Wih + ((size_t)n * 48 + 16 + j) * 6, kL2E);
  mkA(Anh, qt, Whh + ((size_t)n * 48 + 32 + j) * 16, nullptr, 2.0f * kL2E);
  mkA(Anx, qt, nullptr, Wih + ((size_t)n * 48 + 32 + j) * 6, 2.0f * kL2E);
  mkA(Ay1, qt, W1 + ((size_t)n * 16 + j) * 16, nullptr, 1.0f);
  mkA(Ay2, qt, W2 + ((size_t)n * 16 + j) * 16, nullptr, 1.0f);

  // ---- biases as MFMA C operands (scaled to match) ----
  f32x4 Cbr, Cbz, Cbhn, Cbin, Cb1, Cb2;
  float w3r[4];
#pragma unroll
  for (int r = 0; r < 4; ++r) {
    const int gi = n * 48 + 4 * qt + r;
    Cbr[r] = (bih[gi] + bhh[gi]) * kL2E;
    Cbz[r] = (bih[gi + 16] + bhh[gi + 16]) * kL2E;
    Cbin[r] = bih[gi + 32] * 2.0f * kL2E;
    Cbhn[r] = bhh[gi + 32] * 2.0f * kL2E;
    const int hi = n * 16 + 4 * qt + r;
    Cb1[r] = b1[hi];
    Cb2[r] = b2[hi];
    w3r[r] = W3[hi];
  }
  const float b3s = b3[n];

  const int b = bt * 16 + j;
  const float* px =
      x + (size_t)b * kXB + (size_t)n * kS + (qt < 3 ? 2 * qt : 0);
  float* outp = out + ((size_t)n * kB + b) * kT;

  // x ring, depth 2 (lane loads only its quad's 2 comps)
  float2 xr[2];
  xr[0] = *(const float2*)(px + 0 * kNS);
  xr[1] = *(const float2*)(px + 1 * kNS);

  float hprev[4] = {0.f, 0.f, 0.f, 0.f};
  unsigned P0 = 0u, P1 = 0u;

  const f32x4 zero4 = {0.f, 0.f, 0.f, 0.f};
  f32x4 Cy1p = zero4;  // Cy1 issued previous step (time t-2 at step t)
  f32x4 Cy2p = zero4;  // Cy2 issued previous step (time t-3 at step t)
  float s4[4] = {0.f, 0.f, 0.f, 0.f};

  // One pipeline step. doRec: recurrence active (t<kT). doIss: MFMA issue
  // active (t<=kT; t==kT issues only Cy1). Stage B consumes Cy2p (time t-3),
  // stage A consumes Cy1p (time t-2) and issues the new Cy2, stage C
  // reduces+stores times t-6..t-3.
  auto step = [&](int t, bool doRec, bool doA, bool doB, bool doC) {
    f32x4 Cr, Cz, Chn, Cxn, Cy1n = Cy1p;
    if (t <= kT) {
      const int sl = t & 1;
      Frag Bf;
      Bf.u[0] = P0;
      Bf.u[1] = P1;
      Bf.u[2] = (qt < 3) ? pkbf(xr[sl].x, xr[sl].y) : 0u;
      Bf.u[3] = 0u;
      // reload ring slot with x_{t+2} (clamped)
      {
        int tc = t + 2;
        if (tc > kT - 1) tc = kT - 1;
        xr[sl] = *(const float2*)(px + (size_t)tc * kNS);
      }
      if (doRec) {
        Cr = mfma16(Ar.v, Bf.v, Cbr);
        Cz = mfma16(Az.v, Bf.v, Cbz);
        Chn = mfma16(Anh.v, Bf.v, Cbhn);
        Cxn = mfma16(Anx.v, Bf.v, Cbin);
      }
      Cy1n = mfma16(Ay1.v, Bf.v, Cb1);  // y1 pre-act for time t-1
    }

    // stage B: partial s for time t-3 from Cy2p (issued last step; ready)
    if (doB) {
      float s = fmaxf(Cy2p[0], 0.f) * w3r[0];
      s += fmaxf(Cy2p[1], 0.f) * w3r[1];
      s += fmaxf(Cy2p[2], 0.f) * w3r[2];
      s += fmaxf(Cy2p[3], 0.f) * w3r[3];
      s4[(t - 3) & 3] = s;
    }

    // stage A: relu+pack y1(time t-2) from Cy1p, issue Cy2
    if (doA) {
      Frag By;
      By.u[0] = pkbf(fmaxf(Cy1p[0], 0.f), fmaxf(Cy1p[1], 0.f));
      By.u[1] = pkbf(fmaxf(Cy1p[2], 0.f), fmaxf(Cy1p[3], 0.f));
      By.u[2] = 0u;
      By.u[3] = 0u;
      Cy2p = mfma16(Ay2.v, By.v, Cb2);
    }

    // stage C: batched 16-lane reduce + store of times t-6..t-3
    if (doC) {
      float v0 = s4[0], v1 = s4[1], v2 = s4[2], v3 = s4[3];
      v0 += __shfl_xor(v0, 16);
      v1 += __shfl_xor(v1, 16);
      v2 += __shfl_xor(v2, 16);
      v3 += __shfl_xor(v3, 16);
      v0 += __shfl_xor(v0, 32);
      v1 += __shfl_xor(v1, 32);
      v2 += __shfl_xor(v2, 32);
      v3 += __shfl_xor(v3, 32);
      if (qt == 0) {
        float4 o = {fmaxf(v0 + b3s, 0.f), fmaxf(v1 + b3s, 0.f),
                    fmaxf(v2 + b3s, 0.f), fmaxf(v3 + b3s, 0.f)};
        *(float4*)(outp + (t - 6)) = o;
      }
    }

    // gate epilogue -> h_t (exp2-native; weights pre-scaled)
    if (doRec) {
#pragma unroll
      for (int r = 0; r < 4; ++r) {
        const float rr = rcp_fast(1.f + exp2_fast(-Cr[r]));
        const float zz = rcp_fast(1.f + exp2_fast(-Cz[r]));
        const float np = Cxn[r] + rr * Chn[r];
        const float nn = 1.f - 2.f * rcp_fast(1.f + exp2_fast(np));
        hprev[r] = nn + zz * (hprev[r] - nn);
      }
      P0 = pkbf(hprev[0], hprev[1]);
      P1 = pkbf(hprev[2], hprev[3]);
    }

    Cy1p = Cy1n;
  };

  // peel: fill the y pipeline
  step(0, true, false, false, false);
  step(1, true, false, false, false);
  step(2, true, true, false, false);
  step(3, true, true, true, false);

  for (int t4 = 4; t4 < kT; t4 += 4) {
    step(t4 + 0, true, true, true, false);
    step(t4 + 1, true, true, true, false);
    step(t4 + 2, true, true, true, true);  // t%4==2 -> reduce+store
    step(t4 + 3, true, true, true, false);
  }

  // drain: t=128 issues Cy1(127); 129/130 flush stages A/B/C
  step(kT, false, true, true, false);
  step(kT + 1, false, true, true, false);
  step(kT + 2, false, false, true, true);  // stores times 124..127
}

extern "C" void kernel_launch(void* const* d_in, const int* in_sizes, int n_in,
                              void* d_out, int out_size, void* d_ws,
                              size_t ws_size, hipStream_t stream) {
  const float* x = (const float*)d_in[0];
  const float* Wih = (const float*)d_in[1];
  const float* Whh = (const float*)d_in[2];
  const float* bih = (const float*)d_in[3];
  const float* bhh = (const float*)d_in[4];
  const float* W1 = (const float*)d_in[5];
  const float* b1 = (const float*)d_in[6];
  const float* W2 = (const float*)d_in[7];
  const float* b2 = (const float*)d_in[8];
  const float* W3 = (const float*)d_in[9];
  const float* b3 = (const float*)d_in[10];
  float* out = (float*)d_out;

  actor_pipe<<<dim3(kN * 8), dim3(64), 0, stream>>>(x, Wih, Whh, bih, bhh, W1,
                                                    b1, W2, b2, W3, b3, out);
}

// Round 11
// 138.331 us; speedup vs baseline: 1.7343x; 1.0403x over previous
//
#include <hip/hip_runtime.h>

namespace {

constexpr int kN = 100;   // subactors
constexpr int kH = 16;    // hidden
constexpr int kS = 6;     // state
constexpr int kB = 128;   // batch
constexpr int kT = 128;   // time
constexpr int kNS = kN * kS;   // 600 floats per (b,t) row
constexpr int kXB = kT * kNS;  // 76800 floats per b
constexpr float kL2E = 1.44269504088896340736f;  // log2(e)

typedef float f32x4 __attribute__((ext_vector_type(4)));
typedef float vf2 __attribute__((ext_vector_type(2)));
typedef short bf16x8 __attribute__((ext_vector_type(8)));

union Frag {
  unsigned u[4];
  bf16x8 v;
};

// Manual RNE pack of two f32 into one dword of two bf16 (low = a).
// Used for ALL packs feeding MFMA B operands: round 10 showed
// v_cvt_pk_bf16_f32 has different rounding/operand semantics and broke the
// recurrence (absmax 0.226). Do not substitute without an isolated probe.
__device__ __forceinline__ unsigned pkbf(float a, float b) {
  unsigned ua = __builtin_bit_cast(unsigned, a);
  unsigned ub = __builtin_bit_cast(unsigned, b);
  ua += 0x7fffu + ((ua >> 16) & 1u);
  ub += 0x7fffu + ((ub >> 16) & 1u);
  return (ua >> 16) | (ub & 0xffff0000u);
}

__device__ __forceinline__ float rcp_fast(float v) {
  return __builtin_amdgcn_rcpf(v);
}
__device__ __forceinline__ float exp2_fast(float v) {
  return __builtin_amdgcn_exp2f(v);
}
__device__ __forceinline__ vf2 pkfma(vf2 a, vf2 b, vf2 c) {
  return __builtin_elementwise_fma(a, b, c);
}

__device__ __forceinline__ f32x4 mfma16(bf16x8 a, bf16x8 b, f32x4 c) {
  return __builtin_amdgcn_mfma_f32_16x16x32_bf16(a, b, c, 0, 0, 0);
}

// K-slot permutation for lane-local B (A and B just have to agree):
//   quad q supplies k-slots [8q..8q+3] = h rows 4q..4q+3,
//   [8q+4,8q+5] = x comps 2q,2q+1 (q<3), rest 0.
__device__ __forceinline__ void mkA(Frag& F, int qt, const float* hrow,
                                    const float* xrow, float sc) {
  F.u[0] = F.u[1] = F.u[2] = F.u[3] = 0u;
  if (hrow) {
    F.u[0] = pkbf(hrow[4 * qt + 0] * sc, hrow[4 * qt + 1] * sc);
    F.u[1] = pkbf(hrow[4 * qt + 2] * sc, hrow[4 * qt + 3] * sc);
  }
  if (xrow && qt < 3) {
    F.u[2] = pkbf(xrow[2 * qt + 0] * sc, xrow[2 * qt + 1] * sc);
  }
}

}  // namespace

// Wave = (n, 16-batch tile), 800 waves, lane-local B (r8), y-path pipelined
// 2 deep + batched reduce (r9), packed-f32 epilogue/stages + bias-in-C +
// exp2-native activations (r10) with the proven manual RNE bf16 pack (r11).
__global__ __launch_bounds__(64) void actor_pk2(
    const float* __restrict__ x, const float* __restrict__ Wih,
    const float* __restrict__ Whh, const float* __restrict__ bih,
    const float* __restrict__ bhh, const float* __restrict__ W1,
    const float* __restrict__ b1, const float* __restrict__ W2,
    const float* __restrict__ b2, const float* __restrict__ W3,
    const float* __restrict__ b3, float* __restrict__ out) {
  const int tid = (int)threadIdx.x;
  const int j = tid & 15;
  const int qt = tid >> 4;
  const int n = (int)blockIdx.x >> 3;
  const int bt = (int)blockIdx.x & 7;

  // ---- A fragments, K-permuted, log2e-prescaled ----
  Frag Ar, Az, Anh, Anx, Ay1, Ay2;
  mkA(Ar, qt, Whh + ((size_t)n * 48 + j) * 16, Wih + ((size_t)n * 48 + j) * 6,
      kL2E);
  mkA(Az, qt, Whh + ((size_t)n * 48 + 16 + j) * 16,
      Wih + ((size_t)n * 48 + 16 + j) * 6, kL2E);
  mkA(Anh, qt, Whh + ((size_t)n * 48 + 32 + j) * 16, nullptr, 2.0f * kL2E);
  mkA(Anx, qt, nullptr, Wih + ((size_t)n * 48 + 32 + j) * 6, 2.0f * kL2E);
  mkA(Ay1, qt, W1 + ((size_t)n * 16 + j) * 16, nullptr, 1.0f);
  mkA(Ay2, qt, W2 + ((size_t)n * 16 + j) * 16, nullptr, 1.0f);

  // ---- biases as MFMA C operands ----
  f32x4 Cbr, Cbz, Cbhn, Cbin, Cb1, Cb2;
  vf2 w301, w323;
#pragma unroll
  for (int r = 0; r < 4; ++r) {
    const int gi = n * 48 + 4 * qt + r;
    Cbr[r] = (bih[gi] + bhh[gi]) * kL2E;
    Cbz[r] = (bih[gi + 16] + bhh[gi + 16]) * kL2E;
    Cbin[r] = bih[gi + 32] * 2.0f * kL2E;
    Cbhn[r] = bhh[gi + 32] * 2.0f * kL2E;
    const int hi = n * 16 + 4 * qt + r;
    Cb1[r] = b1[hi];
    Cb2[r] = b2[hi];
  }
  w301 = (vf2){W3[n * 16 + 4 * qt + 0], W3[n * 16 + 4 * qt + 1]};
  w323 = (vf2){W3[n * 16 + 4 * qt + 2], W3[n * 16 + 4 * qt + 3]};
  const float b3s = b3[n];

  const int b = bt * 16 + j;
  const float* px =
      x + (size_t)b * kXB + (size_t)n * kS + (qt < 3 ? 2 * qt : 0);
  float* outp = out + ((size_t)n * kB + b) * kT;

  // x ring, depth 4
  float2 xr[4];
#pragma unroll
  for (int i = 0; i < 4; ++i) xr[i] = *(const float2*)(px + (size_t)i * kNS);

  vf2 hp01 = (vf2){0.f, 0.f}, hp23 = (vf2){0.f, 0.f};
  unsigned P0 = 0u, P1 = 0u;

  const f32x4 zero4 = {0.f, 0.f, 0.f, 0.f};
  f32x4 Cy1p = zero4;  // Cy1 issued previous step (time t-2 at step t)
  f32x4 Cy2p = zero4;  // Cy2 issued previous step (time t-3 at step t)
  float s4[4] = {0.f, 0.f, 0.f, 0.f};

  const vf2 one2 = (vf2){1.f, 1.f};
  const vf2 m2 = (vf2){-2.f, -2.f};
  const vf2 z2 = (vf2){0.f, 0.f};

  auto step = [&](int t, bool doRec, bool doA, bool doB, bool doC) {
    f32x4 Cr, Cz, Chn, Cxn, Cy1n = Cy1p;
    if (t <= kT) {
      const int sl = t & 3;
      Frag Bf;
      Bf.u[0] = P0;
      Bf.u[1] = P1;
      Bf.u[2] = (qt < 3) ? pkbf(xr[sl].x, xr[sl].y) : 0u;
      Bf.u[3] = 0u;
      // reload ring slot with x_{t+4} (clamped)
      {
        int tc = t + 4;
        if (tc > kT - 1) tc = kT - 1;
        xr[sl] = *(const float2*)(px + (size_t)tc * kNS);
      }
      if (doRec) {
        Cr = mfma16(Ar.v, Bf.v, Cbr);
        Cz = mfma16(Az.v, Bf.v, Cbz);
        Chn = mfma16(Anh.v, Bf.v, Cbhn);
        Cxn = mfma16(Anx.v, Bf.v, Cbin);
      }
      Cy1n = mfma16(Ay1.v, Bf.v, Cb1);  // y1 pre-act for time t-1
    }

    // stage B: packed partial s for time t-3 from Cy2p
    if (doB) {
      vf2 a = __builtin_elementwise_max((vf2){Cy2p[0], Cy2p[1]}, z2);
      vf2 c = __builtin_elementwise_max((vf2){Cy2p[2], Cy2p[3]}, z2);
      vf2 p = pkfma(c, w323, a * w301);
      s4[(t - 3) & 3] = p.x + p.y;
    }

    // stage A: packed relu + RNE pack of y1(time t-2), issue Cy2
    if (doA) {
      vf2 a = __builtin_elementwise_max((vf2){Cy1p[0], Cy1p[1]}, z2);
      vf2 c = __builtin_elementwise_max((vf2){Cy1p[2], Cy1p[3]}, z2);
      Frag By;
      By.u[0] = pkbf(a.x, a.y);
      By.u[1] = pkbf(c.x, c.y);
      By.u[2] = 0u;
      By.u[3] = 0u;
      Cy2p = mfma16(Ay2.v, By.v, Cb2);
    }

    // stage C: batched 16-lane reduce + float4 store of times t-6..t-3
    if (doC) {
      float v0 = s4[0], v1 = s4[1], v2 = s4[2], v3 = s4[3];
      v0 += __shfl_xor(v0, 16);
      v1 += __shfl_xor(v1, 16);
      v2 += __shfl_xor(v2, 16);
      v3 += __shfl_xor(v3, 16);
      v0 += __shfl_xor(v0, 32);
      v1 += __shfl_xor(v1, 32);
      v2 += __shfl_xor(v2, 32);
      v3 += __shfl_xor(v3, 32);
      if (qt == 0) {
        float4 o = {fmaxf(v0 + b3s, 0.f), fmaxf(v1 + b3s, 0.f),
                    fmaxf(v2 + b3s, 0.f), fmaxf(v3 + b3s, 0.f)};
        *(float4*)(outp + (t - 6)) = o;
      }
    }

    // packed gate epilogue -> h_t
    if (doRec) {
      vf2 cr01 = {Cr[0], Cr[1]}, cr23 = {Cr[2], Cr[3]};
      vf2 cz01 = {Cz[0], Cz[1]}, cz23 = {Cz[2], Cz[3]};
      vf2 chn01 = {Chn[0], Chn[1]}, chn23 = {Chn[2], Chn[3]};
      vf2 cxn01 = {Cxn[0], Cxn[1]}, cxn23 = {Cxn[2], Cxn[3]};

      vf2 er01 = {exp2_fast(-cr01.x), exp2_fast(-cr01.y)};
      vf2 er23 = {exp2_fast(-cr23.x), exp2_fast(-cr23.y)};
      vf2 dr01 = er01 + one2, dr23 = er23 + one2;
      vf2 rr01 = {rcp_fast(dr01.x), rcp_fast(dr01.y)};
      vf2 rr23 = {rcp_fast(dr23.x), rcp_fast(dr23.y)};

      vf2 ez01 = {exp2_fast(-cz01.x), exp2_fast(-cz01.y)};
      vf2 ez23 = {exp2_fast(-cz23.x), exp2_fast(-cz23.y)};
      vf2 dz01 = ez01 + one2, dz23 = ez23 + one2;
      vf2 zz01 = {rcp_fast(dz01.x), rcp_fast(dz01.y)};
      vf2 zz23 = {rcp_fast(dz23.x), rcp_fast(dz23.y)};

      vf2 np01 = pkfma(rr01, chn01, cxn01);
      vf2 np23 = pkfma(rr23, chn23, cxn23);
      vf2 en01 = {exp2_fast(np01.x), exp2_fast(np01.y)};
      vf2 en23 = {exp2_fast(np23.x), exp2_fast(np23.y)};
      vf2 dn01 = en01 + one2, dn23 = en23 + one2;
      vf2 rn01 = {rcp_fast(dn01.x), rcp_fast(dn01.y)};
      vf2 rn23 = {rcp_fast(dn23.x), rcp_fast(dn23.y)};
      vf2 nn01 = pkfma(m2, rn01, one2);
      vf2 nn23 = pkfma(m2, rn23, one2);

      hp01 = pkfma(zz01, hp01 - nn01, nn01);
      hp23 = pkfma(zz23, hp23 - nn23, nn23);
      P0 = pkbf(hp01.x, hp01.y);
      P1 = pkbf(hp23.x, hp23.y);
    }

    Cy1p = Cy1n;
  };

  // peel: fill the y pipeline
  step(0, true, false, false, false);
  step(1, true, false, false, false);
  step(2, true, true, false, false);
  step(3, true, true, true, false);

  for (int t4 = 4; t4 < kT; t4 += 4) {
    step(t4 + 0, true, true, true, false);
    step(t4 + 1, true, true, true, false);
    step(t4 + 2, true, true, true, true);  // reduce+store every 4 steps
    step(t4 + 3, true, true, true, false);
  }

  // drain
  step(kT, false, true, true, false);
  step(kT + 1, false, true, true, false);
  step(kT + 2, false, false, true, true);  // stores times 124..127
}

extern "C" void kernel_launch(void* const* d_in, const int* in_sizes, int n_in,
                              void* d_out, int out_size, void* d_ws,
                              size_t ws_size, hipStream_t stream) {
  const float* x = (const float*)d_in[0];
  const float* Wih = (const float*)d_in[1];
  const float* Whh = (const float*)d_in[2];
  const float* bih = (const float*)d_in[3];
  const float* bhh = (const float*)d_in[4];
  const float* W1 = (const float*)d_in[5];
  const float* b1 = (const float*)d_in[6];
  const float* W2 = (const float*)d_in[7];
  const float* b2 = (const float*)d_in[8];
  const float* W3 = (const float*)d_in[9];
  const float* b3 = (const float*)d_in[10];
  float* out = (float*)d_out;

  actor_pk2<<<dim3(kN * 8), dim3(64), 0, stream>>>(x, Wih, Whh, bih, bhh, W1,
                                                   b1, W2, b2, W3, b3, out);
}